// Round 4
// baseline (14.217 us; speedup 1.0000x reference)
//
#include <hip/hip_runtime.h>
#include <math.h>

// Fused quanvolution + linear + log_softmax, closed-form circuit,
// 2 waves per sample for max occupancy (8192 waves = 32 waves/CU).
//
// Closed form (verified vs the passing amplitude simulation, absmax 1.6e-2):
//   e0 = cos(t0)cos(t4)*cos(p0) - sin(t4)*sin(p0)*sin(p1+t1)
//   e1 = cos(t0)*cos(p0)*cos(p1+t1)
//   e2 = cos(p2)
//   e3 = cos(t3)*cos(p2)*cos(p3)
//
// Block = 256 threads = 4 waves = 2 samples. Wave (2s+h) handles patches
// [98h, 98h+98) of sample s: 1 full 64-lane iteration + 34-lane tail.
// Features are FMA'd straight into acc[10] via coalesced float4 W loads;
// 6-step butterfly per wave; 160B LDS exchange combines the two waves;
// lane-parallel log_softmax, coalesced 40B store.
__global__ __launch_bounds__(256) void quanv_fused_kernel(
    const float* __restrict__ x,      // [B,28,28]
    const float* __restrict__ theta,  // [6]
    const float* __restrict__ W,      // [10,784]
    const float* __restrict__ bias,   // [10]
    float* __restrict__ out,          // [B,10] log-probs
    int B)
{
    __shared__ float red[4][10];

    const int wv   = threadIdx.x >> 6;          // 0..3
    const int lane = threadIdx.x & 63;
    const int half = wv & 1;                    // which patch half
    const int b    = blockIdx.x * 2 + (wv >> 1);
    if (b >= B) return;

    // theta-derived constants (loop-invariant broadcast)
    const float t1 = theta[1];
    const float K1 = __cosf(theta[0]) * __cosf(theta[4]);  // cos t0 cos t4
    const float K2 = __sinf(theta[4]);                     // sin t4
    const float K3 = __cosf(theta[0]);                     // cos t0
    const float K4 = __cosf(theta[3]);                     // cos t3

    const float* __restrict__ xb = x + (size_t)b * 784;

    float acc[10];
#pragma unroll
    for (int k = 0; k < 10; ++k) acc[k] = 0.f;

    auto do_patch = [&](int p) {
        const int r = p / 14, c = p - r * 14;
        const float* px = xb + r * 56 + c * 2;
        const float2 t01 = *reinterpret_cast<const float2*>(px);
        const float2 t23 = *reinterpret_cast<const float2*>(px + 28);

        float sp0, cp0, sph, cph;
        __sincosf(t01.x, &sp0, &cp0);        // sin p0, cos p0
        __sincosf(t01.y + t1, &sph, &cph);   // sin/cos(p1 + t1)
        const float cp2 = __cosf(t23.x);
        const float cp3 = __cosf(t23.y);

        const float e0 = K1 * cp0 - K2 * sp0 * sph;
        const float e1 = K3 * cp0 * cph;
        const float e2 = cp2;
        const float e3 = K4 * cp2 * cp3;

#pragma unroll
        for (int k = 0; k < 10; ++k) {
            const float4 w4 = *reinterpret_cast<const float4*>(&W[k * 784 + 4 * p]);
            acc[k] += e0 * w4.x + e1 * w4.y + e2 * w4.z + e3 * w4.w;
        }
    };

    const int base = half * 98;                 // 98 patches per wave
    do_patch(base + lane);
    if (lane < 34) do_patch(base + 64 + lane);

    // in-wave butterfly: afterwards every lane holds this wave's 10 partials
#pragma unroll
    for (int m = 1; m < 64; m <<= 1) {
#pragma unroll
        for (int k = 0; k < 10; ++k) acc[k] += __shfl_xor(acc[k], m, 64);
    }

    // static-index select so red[] write needs no runtime-indexed array
    float v = acc[0];
#pragma unroll
    for (int k = 1; k < 10; ++k) v = (lane == k) ? acc[k] : v;
    if (lane < 10) red[wv][lane] = v;
    __syncthreads();

    if (half == 0) {
        const int l = (lane < 10) ? lane : 0;
        const float vv = red[wv][l] + red[wv + 1][l] + bias[l];

        float m = (lane < 10) ? vv : -1e30f;
#pragma unroll
        for (int off = 1; off < 16; off <<= 1) m = fmaxf(m, __shfl_xor(m, off, 16));
        float s = (lane < 10) ? __expf(vv - m) : 0.f;
#pragma unroll
        for (int off = 1; off < 16; off <<= 1) s += __shfl_xor(s, off, 16);
        const float lse = m + __logf(s);

        if (lane < 10) out[(size_t)b * 10 + lane] = vv - lse;
    }
}

extern "C" void kernel_launch(void* const* d_in, const int* in_sizes, int n_in,
                              void* d_out, int out_size, void* d_ws, size_t ws_size,
                              hipStream_t stream) {
    const float* x     = (const float*)d_in[0];  // [B,28,28]
    const float* theta = (const float*)d_in[1];  // [6]
    const float* W     = (const float*)d_in[2];  // [10,784]
    const float* bias  = (const float*)d_in[3];  // [10]
    float* out = (float*)d_out;                  // [B,10]

    const int B = in_sizes[0] / 784;             // 4096
    const int blocks = (B + 1) / 2;              // 2 samples per block (4 waves)
    quanv_fused_kernel<<<dim3(blocks), dim3(256), 0, stream>>>(x, theta, W, bias, out, B);
}